// Round 4
// baseline (561.965 us; speedup 1.0000x reference)
//
#include <hip/hip_runtime.h>
#include <stdint.h>

// Output layout (float32 elements within d_out):
//   q_out : [8][1024][64][64]  at offset 0          (33,554,432)
//   code  : [8][4][64][64]     at offset 33,554,432 (131,072)  -- stored as float
//   logit : [8][1024][64][64]  at offset 33,685,504 (33,554,432)
#define CODE_OFF  33554432u
#define LOGIT_OFF 33685504u

typedef __attribute__((address_space(1))) const void g_void;
typedef __attribute__((address_space(3))) void l_void;

__device__ __forceinline__ uint32_t rotl32(uint32_t x, int r) {
  return (x << r) | (x >> (32 - r));
}

// Partitionable threefry (JAX >= 0.4.36 default): counter words (0, flat_idx),
// key (0,42), 20 rounds, draw = o0 ^ o1. Verified bit-exact (round 2/3).
__device__ __forceinline__ uint32_t tf32_part(uint32_t i) {
  const uint32_t ks1 = 42u;
  const uint32_t ks2 = 0x1BD11BDAu ^ 42u;  // ks0 = 0
  uint32_t x0 = 0u;
  uint32_t x1 = i + ks1;
#define R4(a,b,c,d) \
  x0 += x1; x1 = rotl32(x1,(a)); x1 ^= x0; \
  x0 += x1; x1 = rotl32(x1,(b)); x1 ^= x0; \
  x0 += x1; x1 = rotl32(x1,(c)); x1 ^= x0; \
  x0 += x1; x1 = rotl32(x1,(d)); x1 ^= x0;
  R4(13,15,26,6)   x0 += ks1; x1 += ks2 + 1u;
  R4(17,29,16,24)  x0 += ks2; x1 += 2u;
  R4(13,15,26,6)               x1 += ks1 + 3u;
  R4(17,29,16,24)  x0 += ks1; x1 += ks2 + 4u;
  R4(13,15,26,6)   x0 += ks2; x1 += 5u;
#undef R4
  return x0 ^ x1;
}

__device__ __forceinline__ float bits_to_gumbel(uint32_t bits) {
  uint32_t fb = (bits >> 9) | 0x3f800000u;
  float f = __uint_as_float(fb) - 1.0f;
  float u = (f > 0.0f) ? f : 1.17549435e-38f;
  return -logf(-logf(u));
}

// Block: 256 threads, covers one (n<4, m) pair, a 16-wide hw tile, both
// n-halves (n and n+4) -> 32 output rows' worth of positions.
// tx = tid&7: half = tx>>2, px = tx&3 -> 4 consecutive positions hw0+4*px+p.
// ty = tid>>3 in [0,32): owns 8 k's as k = j*128 + ty*4 + d (j<2, d<4).
__global__ __launch_bounds__(256, 6)
void mcq_kernel(const float* __restrict__ x, const float* __restrict__ w,
                float* __restrict__ out) {
  __shared__ __align__(16) float x_lds[2048];  // [c][half*16 + pos], 8 KB
  __shared__ __align__(16) float w_lds[4096];  // [cc][k], 16-c chunk, 16 KB

  const int tid = threadIdx.x;
  const int tx = tid & 7;
  const int ty = tid >> 3;
  const int half = tx >> 2;
  const int px = tx & 3;
  const int bid = blockIdx.x;
  const int nm = bid >> 8;     // n = nm>>2, m = nm&3
  const int tile = bid & 255;
  const int hw0 = tile * 16;
  const int n = nm >> 2;
  const int m = nm & 3;

  float* q_out = out;
  float* code_out = out + CODE_OFF;
  float* logit_out = out + LOGIT_OFF;

  // ---- stage x via global_load_lds (width 16); layout [c][half][pos] ----
  {
    const float* xA = x + (size_t)(n * 256 + m * 64) * 4096 + hw0;
    const float* xB = xA + (size_t)4 * 256 * 4096;
#pragma unroll
    for (int it = 0; it < 2; ++it) {
      int idx = it * 256 + tid;        // float4 slot, 0..511
      int c = idx >> 3;
      int hs = (idx >> 2) & 1;
      int ck = idx & 3;
      const float* src = (hs ? xB : xA) + (size_t)c * 4096 + ck * 4;
      float* dst = x_lds + ((it * 256 + (tid & ~63)) << 2);  // wave-uniform base
      __builtin_amdgcn_global_load_lds((g_void*)src, (l_void*)dst, 16, 0, 0);
    }
  }

  const float* wrow = w + (size_t)m * 256 * 64;  // w[m][k][c], c contiguous
  float4 wr0, wr1, wr2, wr3;
  {  // chunk 0 of w into regs, then transposed to LDS (thread owns k = tid)
    const float* wk = wrow + tid * 64;
    wr0 = *(const float4*)(wk + 0);
    wr1 = *(const float4*)(wk + 4);
    wr2 = *(const float4*)(wk + 8);
    wr3 = *(const float4*)(wk + 12);
    w_lds[ 0 * 256 + tid] = wr0.x; w_lds[ 1 * 256 + tid] = wr0.y;
    w_lds[ 2 * 256 + tid] = wr0.z; w_lds[ 3 * 256 + tid] = wr0.w;
    w_lds[ 4 * 256 + tid] = wr1.x; w_lds[ 5 * 256 + tid] = wr1.y;
    w_lds[ 6 * 256 + tid] = wr1.z; w_lds[ 7 * 256 + tid] = wr1.w;
    w_lds[ 8 * 256 + tid] = wr2.x; w_lds[ 9 * 256 + tid] = wr2.y;
    w_lds[10 * 256 + tid] = wr2.z; w_lds[11 * 256 + tid] = wr2.w;
    w_lds[12 * 256 + tid] = wr3.x; w_lds[13 * 256 + tid] = wr3.y;
    w_lds[14 * 256 + tid] = wr3.z; w_lds[15 * 256 + tid] = wr3.w;
  }
  __syncthreads();  // drains x lds-loads (vmcnt) + w writes

  // accumulators: acc{p}[jd], p = 0..3 position offset; jd -> k = (jd>>2)*128 + ty*4 + (jd&3)
  float acc0[8], acc1[8], acc2[8], acc3[8];
#pragma unroll
  for (int i = 0; i < 8; ++i) acc0[i] = acc1[i] = acc2[i] = acc3[i] = 0.0f;

#pragma unroll
  for (int chunk = 0; chunk < 4; ++chunk) {
    if (chunk < 3) {  // prefetch next w chunk into regs (retires under compute)
      const float* wk = wrow + tid * 64 + (chunk + 1) * 16;
      wr0 = *(const float4*)(wk + 0);
      wr1 = *(const float4*)(wk + 4);
      wr2 = *(const float4*)(wk + 8);
      wr3 = *(const float4*)(wk + 12);
    }
#pragma unroll
    for (int cc = 0; cc < 16; ++cc) {
      int c = chunk * 16 + cc;
      float4 xv = *(const float4*)&x_lds[c * 32 + half * 16 + px * 4];
      float wv[8];
      *(float4*)&wv[0] = *(const float4*)&w_lds[cc * 256 +   0 + ty * 4];
      *(float4*)&wv[4] = *(const float4*)&w_lds[cc * 256 + 128 + ty * 4];
#pragma unroll
      for (int jd = 0; jd < 8; ++jd) {
        float wkv = wv[jd];
        acc0[jd] += xv.x * wkv;
        acc1[jd] += xv.y * wkv;
        acc2[jd] += xv.z * wkv;
        acc3[jd] += xv.w * wkv;
      }
    }
    if (chunk < 3) {
      __syncthreads();  // compute on w_lds done
      w_lds[ 0 * 256 + tid] = wr0.x; w_lds[ 1 * 256 + tid] = wr0.y;
      w_lds[ 2 * 256 + tid] = wr0.z; w_lds[ 3 * 256 + tid] = wr0.w;
      w_lds[ 4 * 256 + tid] = wr1.x; w_lds[ 5 * 256 + tid] = wr1.y;
      w_lds[ 6 * 256 + tid] = wr1.z; w_lds[ 7 * 256 + tid] = wr1.w;
      w_lds[ 8 * 256 + tid] = wr2.x; w_lds[ 9 * 256 + tid] = wr2.y;
      w_lds[10 * 256 + tid] = wr2.z; w_lds[11 * 256 + tid] = wr2.w;
      w_lds[12 * 256 + tid] = wr3.x; w_lds[13 * 256 + tid] = wr3.y;
      w_lds[14 * 256 + tid] = wr3.z; w_lds[15 * 256 + tid] = wr3.w;
      __syncthreads();
    }
  }

  // ---- epilogue: float4 logit stores + gumbel + per-thread argmax ----
  float best0 = -3.4e38f, best1 = -3.4e38f, best2 = -3.4e38f, best3 = -3.4e38f;
  int i0 = 0, i1 = 0, i2 = 0, i3 = 0;
  // flat index = ((nm + 16*half)*4096 + hw) * 256 + k, hw = hw0 + 4*px + p
  const uint32_t base0 = ((uint32_t)((nm + 16 * half) * 4096 + hw0 + 4 * px)) << 8;
  const size_t row_off = (size_t)hw0 + 4 * px;
#pragma unroll
  for (int jd = 0; jd < 8; ++jd) {
    int k = (jd >> 2) * 128 + ty * 4 + (jd & 3);
    size_t off = (size_t)((nm + 16 * half) * 256 + k) * 4096 + row_off;
    *(float4*)(logit_out + off) = make_float4(acc0[jd], acc1[jd], acc2[jd], acc3[jd]);
    uint32_t b0 = tf32_part(base0 + 0u * 256u + (uint32_t)k);
    uint32_t b1 = tf32_part(base0 + 1u * 256u + (uint32_t)k);
    uint32_t b2 = tf32_part(base0 + 2u * 256u + (uint32_t)k);
    uint32_t b3 = tf32_part(base0 + 3u * 256u + (uint32_t)k);
    float v0 = bits_to_gumbel(b0) + acc0[jd];
    float v1 = bits_to_gumbel(b1) + acc1[jd];
    float v2 = bits_to_gumbel(b2) + acc2[jd];
    float v3 = bits_to_gumbel(b3) + acc3[jd];
    if (v0 > best0) { best0 = v0; i0 = k; }
    if (v1 > best1) { best1 = v1; i1 = k; }
    if (v2 > best2) { best2 = v2; i2 = k; }
    if (v3 > best3) { best3 = v3; i3 = k; }
  }

  // ---- cross-thread argmax reduction over the 32 k-owners (ty) ----
  __syncthreads();  // all GEMM reads of w_lds done; reuse it
  float* red_val = w_lds;               // [32 slots][33]
  int* red_idx = (int*)(w_lds + 1056);  // [32 slots][33]
  {
    int slot = half * 16 + px * 4;      // position slot within block
    red_val[(slot + 0) * 33 + ty] = best0;  red_idx[(slot + 0) * 33 + ty] = i0;
    red_val[(slot + 1) * 33 + ty] = best1;  red_idx[(slot + 1) * 33 + ty] = i1;
    red_val[(slot + 2) * 33 + ty] = best2;  red_idx[(slot + 2) * 33 + ty] = i2;
    red_val[(slot + 3) * 33 + ty] = best3;  red_idx[(slot + 3) * 33 + ty] = i3;
  }
  __syncthreads();
  int* idx_final = (int*)x_lds;  // 32 ints; x_lds no longer needed
  if (tid < 32) {
    float bv = -3.4e38f; int bi = 0x7fffffff;
#pragma unroll
    for (int t2 = 0; t2 < 32; ++t2) {
      float v = red_val[tid * 33 + t2];
      int ix = red_idx[tid * 33 + t2];
      if (v > bv || (v == bv && ix < bi)) { bv = v; bi = ix; }  // tie -> smallest k
    }
    idx_final[tid] = bi;
    int h = tid >> 4;
    int pos = tid & 15;
    code_out[(size_t)(nm + 16 * h) * 4096 + hw0 + pos] = (float)bi;
  }
  __syncthreads();

  // ---- one-hot q_out (race-free: every k written by its owner thread) ----
  const int f0 = idx_final[half * 16 + px * 4 + 0];
  const int f1 = idx_final[half * 16 + px * 4 + 1];
  const int f2 = idx_final[half * 16 + px * 4 + 2];
  const int f3 = idx_final[half * 16 + px * 4 + 3];
#pragma unroll
  for (int jd = 0; jd < 8; ++jd) {
    int k = (jd >> 2) * 128 + ty * 4 + (jd & 3);
    size_t off = (size_t)((nm + 16 * half) * 256 + k) * 4096 + row_off;
    *(float4*)(q_out + off) = make_float4(k == f0 ? 1.0f : 0.0f, k == f1 ? 1.0f : 0.0f,
                                          k == f2 ? 1.0f : 0.0f, k == f3 ? 1.0f : 0.0f);
  }
}

extern "C" void kernel_launch(void* const* d_in, const int* in_sizes, int n_in,
                              void* d_out, int out_size, void* d_ws, size_t ws_size,
                              hipStream_t stream) {
  const float* x = (const float*)d_in[0];  // [8][256][64][64] fp32
  const float* w = (const float*)d_in[1];  // [4][256][64] fp32
  float* out = (float*)d_out;
  mcq_kernel<<<dim3(4096), dim3(256), 0, stream>>>(x, w, out);
}

// Round 5
// 418.705 us; speedup vs baseline: 1.3421x; 1.3421x over previous
//
#include <hip/hip_runtime.h>
#include <stdint.h>

// Output layout (float32 elements within d_out):
//   q_out : [8][1024][64][64]  at offset 0          (33,554,432)
//   code  : [8][4][64][64]     at offset 33,554,432 (131,072)  -- stored as float
//   logit : [8][1024][64][64]  at offset 33,685,504 (33,554,432)
#define CODE_OFF  33554432u
#define LOGIT_OFF 33685504u

typedef __attribute__((address_space(1))) const void g_void;
typedef __attribute__((address_space(3))) void l_void;

__device__ __forceinline__ uint32_t rotl32(uint32_t x, int r) {
  return (x << r) | (x >> (32 - r));
}

// Partitionable threefry (JAX >= 0.4.36 default): counter words (0, flat_idx),
// key (0,42), 20 rounds, draw = o0 ^ o1. Verified bit-exact (rounds 2-4).
__device__ __forceinline__ uint32_t tf32_part(uint32_t i) {
  const uint32_t ks1 = 42u;
  const uint32_t ks2 = 0x1BD11BDAu ^ 42u;  // ks0 = 0
  uint32_t x0 = 0u;
  uint32_t x1 = i + ks1;
#define R4(a,b,c,d) \
  x0 += x1; x1 = rotl32(x1,(a)); x1 ^= x0; \
  x0 += x1; x1 = rotl32(x1,(b)); x1 ^= x0; \
  x0 += x1; x1 = rotl32(x1,(c)); x1 ^= x0; \
  x0 += x1; x1 = rotl32(x1,(d)); x1 ^= x0;
  R4(13,15,26,6)   x0 += ks1; x1 += ks2 + 1u;
  R4(17,29,16,24)  x0 += ks2; x1 += 2u;
  R4(13,15,26,6)               x1 += ks1 + 3u;
  R4(17,29,16,24)  x0 += ks1; x1 += ks2 + 4u;
  R4(13,15,26,6)   x0 += ks2; x1 += 5u;
#undef R4
  return x0 ^ x1;
}

__device__ __forceinline__ float bits_to_gumbel(uint32_t bits) {
  uint32_t fb = (bits >> 9) | 0x3f800000u;
  float f = __uint_as_float(fb) - 1.0f;
  float u = (f > 0.0f) ? f : 1.17549435e-38f;
  return -logf(-logf(u));
}

// Block: 256 threads, covers one (n<4, m, half) and a FULL 64-wide hw row, so
// every output row segment is 64 floats = 256 B (line-aligned, block-exclusive
// -> no cross-block partial-line RMW; round-4 regression showed 64 B segments
// inflate HBM traffic 3x).
// tx = tid&15 -> 4 consecutive positions hw0 + 4*tx + p.
// ty = tid>>4 in [0,16): owns 16 k's as k = j*64 + ty*4 + d (j<4, d<4).
__global__ __launch_bounds__(256, 5)
void mcq_kernel(const float* __restrict__ x, const float* __restrict__ w,
                float* __restrict__ out) {
  __shared__ __align__(16) float x_lds[4096];  // [c][pos], 64x64, 16 KB
  __shared__ __align__(16) float w_lds[4096];  // [cc][k], 16-c chunk, 16 KB

  const int tid = threadIdx.x;
  const int tx = tid & 15;
  const int ty = tid >> 4;
  const int bid = blockIdx.x;
  const int nmh = bid >> 6;    // 0..31: half = nmh>>4, nm = nmh&15
  const int tile = bid & 63;
  const int hw0 = tile * 64;
  const int half = nmh >> 4;
  const int nm = nmh & 15;     // n = nm>>2, m = nm&3
  const int n = nm >> 2;
  const int m = nm & 3;

  float* q_out = out;
  float* code_out = out + CODE_OFF;
  float* logit_out = out + LOGIT_OFF;

  // ---- stage x via global_load_lds (width 16); layout [c][pos] ----
  {
    const float* xbase = x + (size_t)((n + 4 * half) * 256 + m * 64) * 4096 + hw0;
#pragma unroll
    for (int it = 0; it < 4; ++it) {
      int idx = it * 256 + tid;        // float4 slot, 0..1023
      int c = idx >> 4;
      int ck = idx & 15;
      const float* src = xbase + (size_t)c * 4096 + ck * 4;
      float* dst = x_lds + ((it * 256 + (tid & ~63)) << 2);  // wave-uniform base
      __builtin_amdgcn_global_load_lds((g_void*)src, (l_void*)dst, 16, 0, 0);
    }
  }

  const float* wrow = w + (size_t)m * 256 * 64;  // w[m][k][c], c contiguous
  float4 wr0, wr1, wr2, wr3;
  {  // chunk 0 of w into regs, then transposed to LDS (thread owns k = tid)
    const float* wk = wrow + tid * 64;
    wr0 = *(const float4*)(wk + 0);
    wr1 = *(const float4*)(wk + 4);
    wr2 = *(const float4*)(wk + 8);
    wr3 = *(const float4*)(wk + 12);
    w_lds[ 0 * 256 + tid] = wr0.x; w_lds[ 1 * 256 + tid] = wr0.y;
    w_lds[ 2 * 256 + tid] = wr0.z; w_lds[ 3 * 256 + tid] = wr0.w;
    w_lds[ 4 * 256 + tid] = wr1.x; w_lds[ 5 * 256 + tid] = wr1.y;
    w_lds[ 6 * 256 + tid] = wr1.z; w_lds[ 7 * 256 + tid] = wr1.w;
    w_lds[ 8 * 256 + tid] = wr2.x; w_lds[ 9 * 256 + tid] = wr2.y;
    w_lds[10 * 256 + tid] = wr2.z; w_lds[11 * 256 + tid] = wr2.w;
    w_lds[12 * 256 + tid] = wr3.x; w_lds[13 * 256 + tid] = wr3.y;
    w_lds[14 * 256 + tid] = wr3.z; w_lds[15 * 256 + tid] = wr3.w;
  }
  __syncthreads();  // drains x lds-loads (vmcnt) + w writes

  // accumulators: acc{p}[jd], p = 0..3 position offset; jd -> k = (jd>>2)*64 + ty*4 + (jd&3)
  float acc0[16], acc1[16], acc2[16], acc3[16];
#pragma unroll
  for (int i = 0; i < 16; ++i) acc0[i] = acc1[i] = acc2[i] = acc3[i] = 0.0f;

#pragma unroll
  for (int chunk = 0; chunk < 4; ++chunk) {
    if (chunk < 3) {  // prefetch next w chunk into regs (retires under compute)
      const float* wk = wrow + tid * 64 + (chunk + 1) * 16;
      wr0 = *(const float4*)(wk + 0);
      wr1 = *(const float4*)(wk + 4);
      wr2 = *(const float4*)(wk + 8);
      wr3 = *(const float4*)(wk + 12);
    }
#pragma unroll
    for (int cc = 0; cc < 16; ++cc) {
      int c = chunk * 16 + cc;
      float4 xv = *(const float4*)&x_lds[c * 64 + tx * 4];
      float wv[16];
      *(float4*)&wv[0]  = *(const float4*)&w_lds[cc * 256 +   0 + ty * 4];
      *(float4*)&wv[4]  = *(const float4*)&w_lds[cc * 256 +  64 + ty * 4];
      *(float4*)&wv[8]  = *(const float4*)&w_lds[cc * 256 + 128 + ty * 4];
      *(float4*)&wv[12] = *(const float4*)&w_lds[cc * 256 + 192 + ty * 4];
#pragma unroll
      for (int jd = 0; jd < 16; ++jd) {
        float wkv = wv[jd];
        acc0[jd] += xv.x * wkv;
        acc1[jd] += xv.y * wkv;
        acc2[jd] += xv.z * wkv;
        acc3[jd] += xv.w * wkv;
      }
    }
    if (chunk < 3) {
      __syncthreads();  // compute on w_lds done
      w_lds[ 0 * 256 + tid] = wr0.x; w_lds[ 1 * 256 + tid] = wr0.y;
      w_lds[ 2 * 256 + tid] = wr0.z; w_lds[ 3 * 256 + tid] = wr0.w;
      w_lds[ 4 * 256 + tid] = wr1.x; w_lds[ 5 * 256 + tid] = wr1.y;
      w_lds[ 6 * 256 + tid] = wr1.z; w_lds[ 7 * 256 + tid] = wr1.w;
      w_lds[ 8 * 256 + tid] = wr2.x; w_lds[ 9 * 256 + tid] = wr2.y;
      w_lds[10 * 256 + tid] = wr2.z; w_lds[11 * 256 + tid] = wr2.w;
      w_lds[12 * 256 + tid] = wr3.x; w_lds[13 * 256 + tid] = wr3.y;
      w_lds[14 * 256 + tid] = wr3.z; w_lds[15 * 256 + tid] = wr3.w;
      __syncthreads();
    }
  }

  // ---- epilogue: float4 logit stores + gumbel + per-thread argmax ----
  float best0 = -3.4e38f, best1 = -3.4e38f, best2 = -3.4e38f, best3 = -3.4e38f;
  int i0 = 0, i1 = 0, i2 = 0, i3 = 0;
  // flat index = ((nm + 16*half)*4096 + hw) * 256 + k, hw = hw0 + 4*tx + p
  const int rowb = nm + 16 * half;
  const uint32_t base0 = ((uint32_t)(rowb * 4096 + hw0 + 4 * tx)) << 8;
  const size_t row_off = (size_t)hw0 + 4 * tx;
#pragma unroll
  for (int jd = 0; jd < 16; ++jd) {
    int k = (jd >> 2) * 64 + ty * 4 + (jd & 3);
    size_t off = (size_t)(rowb * 256 + k) * 4096 + row_off;
    *(float4*)(logit_out + off) = make_float4(acc0[jd], acc1[jd], acc2[jd], acc3[jd]);
    uint32_t b0 = tf32_part(base0 + 0u * 256u + (uint32_t)k);
    uint32_t b1 = tf32_part(base0 + 1u * 256u + (uint32_t)k);
    uint32_t b2 = tf32_part(base0 + 2u * 256u + (uint32_t)k);
    uint32_t b3 = tf32_part(base0 + 3u * 256u + (uint32_t)k);
    float v0 = bits_to_gumbel(b0) + acc0[jd];
    float v1 = bits_to_gumbel(b1) + acc1[jd];
    float v2 = bits_to_gumbel(b2) + acc2[jd];
    float v3 = bits_to_gumbel(b3) + acc3[jd];
    if (v0 > best0) { best0 = v0; i0 = k; }
    if (v1 > best1) { best1 = v1; i1 = k; }
    if (v2 > best2) { best2 = v2; i2 = k; }
    if (v3 > best3) { best3 = v3; i3 = k; }
  }

  // ---- cross-thread argmax reduction over the 16 k-owners (ty) ----
  __syncthreads();  // all GEMM reads of w_lds done; reuse it
  float* red_val = w_lds;               // [64 slots][17]
  int* red_idx = (int*)(w_lds + 1088);  // [64 slots][17]
  {
    int slot = tx * 4;                  // position slot within block
    red_val[(slot + 0) * 17 + ty] = best0;  red_idx[(slot + 0) * 17 + ty] = i0;
    red_val[(slot + 1) * 17 + ty] = best1;  red_idx[(slot + 1) * 17 + ty] = i1;
    red_val[(slot + 2) * 17 + ty] = best2;  red_idx[(slot + 2) * 17 + ty] = i2;
    red_val[(slot + 3) * 17 + ty] = best3;  red_idx[(slot + 3) * 17 + ty] = i3;
  }
  __syncthreads();
  int* idx_final = (int*)x_lds;  // 64 ints; x_lds no longer needed
  if (tid < 64) {
    float bv = -3.4e38f; int bi = 0x7fffffff;
#pragma unroll
    for (int t2 = 0; t2 < 16; ++t2) {
      float v = red_val[tid * 17 + t2];
      int ix = red_idx[tid * 17 + t2];
      if (v > bv || (v == bv && ix < bi)) { bv = v; bi = ix; }  // tie -> smallest k
    }
    idx_final[tid] = bi;
    code_out[(size_t)rowb * 4096 + hw0 + tid] = (float)bi;  // 256 B segment
  }
  __syncthreads();

  // ---- one-hot q_out (race-free: every k written by its owner thread) ----
  const int f0 = idx_final[tx * 4 + 0];
  const int f1 = idx_final[tx * 4 + 1];
  const int f2 = idx_final[tx * 4 + 2];
  const int f3 = idx_final[tx * 4 + 3];
#pragma unroll
  for (int jd = 0; jd < 16; ++jd) {
    int k = (jd >> 2) * 64 + ty * 4 + (jd & 3);
    size_t off = (size_t)(rowb * 256 + k) * 4096 + row_off;
    *(float4*)(q_out + off) = make_float4(k == f0 ? 1.0f : 0.0f, k == f1 ? 1.0f : 0.0f,
                                          k == f2 ? 1.0f : 0.0f, k == f3 ? 1.0f : 0.0f);
  }
}

extern "C" void kernel_launch(void* const* d_in, const int* in_sizes, int n_in,
                              void* d_out, int out_size, void* d_ws, size_t ws_size,
                              hipStream_t stream) {
  const float* x = (const float*)d_in[0];  // [8][256][64][64] fp32
  const float* w = (const float*)d_in[1];  // [4][256][64] fp32
  float* out = (float*)d_out;
  mcq_kernel<<<dim3(2048), dim3(256), 0, stream>>>(x, w, out);
}